// Round 5
// baseline (233.420 us; speedup 1.0000x reference)
//
#include <hip/hip_runtime.h>

// x: [4096, 8192] fp32. depth: [3] fp32.
// out: [4096, 3, 1024] uint8 values, stored by the harness as int32 (integer output path).
// One thread per 4 consecutive byte-positions: reads 32 consecutive floats
// (8 x dwordx4, 128 B/lane contiguous), writes one int4 (16 B) per threshold plane.
// Non-temporal: streaming data, zero reuse.

typedef float nfloat4 __attribute__((ext_vector_type(4)));  // native vecs for nontemporal builtins
typedef int   nint4   __attribute__((ext_vector_type(4)));

constexpr int ROWS = 4096;
constexpr int COLS = 8192;                   // floats per row
constexpr int BYTES_PER_ROW = COLS / 8;      // 1024 packed bytes per row per depth
constexpr int TOTAL = ROWS * BYTES_PER_ROW;  // 4,194,304 byte-positions per plane
constexpr int BLOCK = 256;
constexpr int GROUPS = TOTAL / 4;            // 1,048,576 four-byte groups
constexpr int GRID = GROUPS / BLOCK;         // 4096 blocks

__global__ __launch_bounds__(BLOCK) void binarize_pack_kernel(
    const float* __restrict__ x,
    const float* __restrict__ depth,
    int* __restrict__ out) {
    const int g = blockIdx.x * BLOCK + threadIdx.x;  // 4-byte-group index

    const float d0 = depth[0];
    const float d1 = depth[1];
    const float d2 = depth[2];

    // 32 consecutive floats: lane i covers bytes [128*i, 128*i+128)
    const nfloat4* xv = reinterpret_cast<const nfloat4*>(x) + (size_t)g * 8;
    nfloat4 r[8];
#pragma unroll
    for (int i = 0; i < 8; ++i) r[i] = __builtin_nontemporal_load(xv + i);

    float v[32];
#pragma unroll
    for (int i = 0; i < 8; ++i) {
        v[4 * i + 0] = r[i].x;
        v[4 * i + 1] = r[i].y;
        v[4 * i + 2] = r[i].z;
        v[4 * i + 3] = r[i].w;
    }

    nint4 o0, o1, o2;
#pragma unroll
    for (int b = 0; b < 4; ++b) {  // 4 output bytes, 8 values each
        unsigned p0 = 0, p1 = 0, p2 = 0;
#pragma unroll
        for (int k = 0; k < 8; ++k) {
            const unsigned w = 1u << (7 - k);  // big-endian bit order
            const float val = v[8 * b + k];
            p0 |= (val > d0) ? w : 0u;
            p1 |= (val > d1) ? w : 0u;
            p2 |= (val > d2) ? w : 0u;
        }
        o0[b] = (int)p0;
        o1[b] = (int)p1;
        o2[b] = (int)p2;
    }

    const int byte0 = g * 4;             // first byte-position of this group
    const int row = byte0 >> 10;         // / BYTES_PER_ROW
    const int col = byte0 & 1023;        // % BYTES_PER_ROW (multiple of 4)
    int* o = out + (size_t)row * (3 * BYTES_PER_ROW) + col;
    __builtin_nontemporal_store(o0, reinterpret_cast<nint4*>(o + 0 * BYTES_PER_ROW));
    __builtin_nontemporal_store(o1, reinterpret_cast<nint4*>(o + 1 * BYTES_PER_ROW));
    __builtin_nontemporal_store(o2, reinterpret_cast<nint4*>(o + 2 * BYTES_PER_ROW));
}

extern "C" void kernel_launch(void* const* d_in, const int* in_sizes, int n_in,
                              void* d_out, int out_size, void* d_ws, size_t ws_size,
                              hipStream_t stream) {
    const float* x = (const float*)d_in[0];
    const float* depth = (const float*)d_in[1];
    int* out = (int*)d_out;

    binarize_pack_kernel<<<GRID, BLOCK, 0, stream>>>(x, depth, out);
}

// Round 6
// 193.993 us; speedup vs baseline: 1.2032x; 1.2032x over previous
//
#include <hip/hip_runtime.h>

// x: [4096, 8192] fp32. depth: [3] fp32.
// out: [4096, 3, 1024] uint8 values, stored by harness as int32.
//
// One block per row. Two phases through LDS so that EVERY global memory
// instruction is perfectly lane-contiguous:
//   1) block loads the row as 8 x (256 lanes x float4) = 4 KB contiguous per
//      instruction, stores to LDS with XOR swizzle (conflict-free both phases).
//   2) each thread reads its 32 consecutive floats from LDS (8 x ds_read_b128,
//      conflict-free), packs 4 output bytes x 3 planes, stores one int4 per
//      plane -> 1 KB contiguous per wave instruction per plane.
// Non-temporal everywhere: every line is fully consumed by one instruction.

typedef float nfloat4 __attribute__((ext_vector_type(4)));
typedef int   nint4   __attribute__((ext_vector_type(4)));

constexpr int ROWS = 4096;
constexpr int COLS = 8192;               // floats per row
constexpr int BYTES_PER_ROW = COLS / 8;  // 1024 packed bytes per row per plane
constexpr int BLOCK = 256;
constexpr int VEC_PER_ROW = COLS / 4;    // 2048 float4 slots per row

__device__ __forceinline__ int swz(int p) {  // XOR-swizzle low 3 bits with bits 3..5
    return p ^ ((p >> 3) & 7);
}

__global__ __launch_bounds__(BLOCK) void binarize_pack_kernel(
    const float* __restrict__ x,
    const float* __restrict__ depth,
    int* __restrict__ out) {
    __shared__ nfloat4 lds[VEC_PER_ROW];  // 32 KB

    const int row = blockIdx.x;
    const int tid = threadIdx.x;

    const float d0 = depth[0];
    const float d1 = depth[1];
    const float d2 = depth[2];

    // Phase 1: perfectly coalesced row load -> swizzled LDS
    const nfloat4* xrow = reinterpret_cast<const nfloat4*>(x) + (size_t)row * VEC_PER_ROW;
#pragma unroll
    for (int j = 0; j < 8; ++j) {
        const int p = j * BLOCK + tid;                       // lane-contiguous
        lds[swz(p)] = __builtin_nontemporal_load(xrow + p);
    }
    __syncthreads();

    // Phase 2: each thread owns floats [32*tid, 32*tid+32)
    float v[32];
#pragma unroll
    for (int j = 0; j < 8; ++j) {
        const nfloat4 q = lds[swz(8 * tid + j)];             // conflict-free via swizzle
        v[4 * j + 0] = q.x;
        v[4 * j + 1] = q.y;
        v[4 * j + 2] = q.z;
        v[4 * j + 3] = q.w;
    }

    nint4 o0, o1, o2;
#pragma unroll
    for (int b = 0; b < 4; ++b) {  // 4 output bytes, 8 values each
        unsigned p0 = 0, p1 = 0, p2 = 0;
#pragma unroll
        for (int k = 0; k < 8; ++k) {
            const unsigned w = 1u << (7 - k);  // big-endian bit order
            const float val = v[8 * b + k];
            p0 |= (val > d0) ? w : 0u;
            p1 |= (val > d1) ? w : 0u;
            p2 |= (val > d2) ? w : 0u;
        }
        o0[b] = (int)p0;
        o1[b] = (int)p1;
        o2[b] = (int)p2;
    }

    // Phase 3: per plane, block writes 1024 int32 = 4 KB contiguous
    int* orow = out + (size_t)row * (3 * BYTES_PER_ROW);
    __builtin_nontemporal_store(o0, reinterpret_cast<nint4*>(orow + 0 * BYTES_PER_ROW) + tid);
    __builtin_nontemporal_store(o1, reinterpret_cast<nint4*>(orow + 1 * BYTES_PER_ROW) + tid);
    __builtin_nontemporal_store(o2, reinterpret_cast<nint4*>(orow + 2 * BYTES_PER_ROW) + tid);
}

extern "C" void kernel_launch(void* const* d_in, const int* in_sizes, int n_in,
                              void* d_out, int out_size, void* d_ws, size_t ws_size,
                              hipStream_t stream) {
    const float* x = (const float*)d_in[0];
    const float* depth = (const float*)d_in[1];
    int* out = (int*)d_out;

    binarize_pack_kernel<<<ROWS, BLOCK, 0, stream>>>(x, depth, out);
}